// Round 1
// baseline (940.473 us; speedup 1.0000x reference)
//
#include <hip/hip_runtime.h>
#include <hip/hip_bf16.h>
#include <math.h>

// CrossTransformerBlock3D: D=H=W=32, DIM=192, HEADS=12, HD=16, WS=2x2x2
// nW=4096 windows, N=8 queries/window, M=216 keys/window (3x3x3 neighborhood)
// Key optimization vs reference: project K/V ONCE per base token (32768 rows)
// instead of per gathered row (884736 rows) -- 27x fewer KV-projection FLOPs.
// Zero slabs (slab==20 and out-of-range padding) have k=bkv[0:192], v=bkv[192:384].

#define TOK 32768
#define NWIN 4096

enum { EP_PLAIN = 0, EP_SPLIT = 1, EP_RESID = 2, EP_GELU = 3 };

// ---------------- LayerNorm: one wave per token, 4 tokens per block ----------
__global__ __launch_bounds__(256) void ln_kernel(const float* __restrict__ in,
                                                 float* __restrict__ out,
                                                 const float* __restrict__ g,
                                                 const float* __restrict__ b) {
  int token = blockIdx.x * 4 + (threadIdx.x >> 6);
  int lane = threadIdx.x & 63;
  const float* row = in + (size_t)token * 192;
  float v0 = row[lane], v1 = row[lane + 64], v2 = row[lane + 128];
  float s = v0 + v1 + v2;
#pragma unroll
  for (int off = 32; off; off >>= 1) s += __shfl_xor(s, off);
  float mean = s * (1.f / 192.f);
  float d0 = v0 - mean, d1 = v1 - mean, d2 = v2 - mean;
  float vs = d0 * d0 + d1 * d1 + d2 * d2;
#pragma unroll
  for (int off = 32; off; off >>= 1) vs += __shfl_xor(vs, off);
  float rstd = rsqrtf(vs * (1.f / 192.f) + 1e-5f);
  float* orow = out + (size_t)token * 192;
  orow[lane] = d0 * rstd * g[lane] + b[lane];
  orow[lane + 64] = d1 * rstd * g[lane + 64] + b[lane + 64];
  orow[lane + 128] = d2 * rstd * g[lane + 128] + b[lane + 128];
}

// ---------------- fp32 GEMM, 64x64 tile, 4x4 per-thread micro-tile ----------
// A [TOK,K] row-major, B [K,N] row-major, bias [N].
// EP_PLAIN: C0 = A@B + bias
// EP_SPLIT: cols<192 -> C0 [TOK,192], cols>=192 -> C1 [TOK,192]   (K/V split)
// EP_RESID: C0 = A@B + bias + resid
// EP_GELU : C0 = gelu_exact(A@B + bias)
template <int EPI, int K, int N>
__global__ __launch_bounds__(256) void gemm_ep(const float* __restrict__ A,
                                               const float* __restrict__ B,
                                               const float* __restrict__ bias,
                                               const float* __restrict__ resid,
                                               float* __restrict__ C0,
                                               float* __restrict__ C1) {
  __shared__ float As[16][68];  // [k][m], pad 68 floats: 16B-aligned rows, no write conflicts
  __shared__ float Bs[16][68];  // [k][n]
  const int tid = threadIdx.x;
  const int tx = tid & 15, ty = tid >> 4;
  const int rb = blockIdx.x * 64;
  const int nb = blockIdx.y * 64;
  float acc[4][4] = {};

#pragma unroll 1
  for (int k0 = 0; k0 < K; k0 += 16) {
    // stage A: 64 rows x 16 k  (consecutive lanes -> consecutive k: coalesced)
#pragma unroll
    for (int p = 0; p < 4; ++p) {
      int idx = tid + p * 256;
      int kk = idx & 15, row = idx >> 4;
      As[kk][row] = A[(size_t)(rb + row) * K + k0 + kk];
    }
    // stage B: 16 k x 64 n  (consecutive lanes -> consecutive n: coalesced)
#pragma unroll
    for (int p = 0; p < 4; ++p) {
      int idx = tid + p * 256;
      int n = idx & 63, kk = idx >> 6;
      Bs[kk][n] = B[(size_t)(k0 + kk) * N + nb + n];
    }
    __syncthreads();
#pragma unroll
    for (int kk = 0; kk < 16; ++kk) {
      float a0 = As[kk][ty * 4 + 0], a1 = As[kk][ty * 4 + 1];
      float a2 = As[kk][ty * 4 + 2], a3 = As[kk][ty * 4 + 3];
      float b0 = Bs[kk][tx * 4 + 0], b1 = Bs[kk][tx * 4 + 1];
      float b2 = Bs[kk][tx * 4 + 2], b3 = Bs[kk][tx * 4 + 3];
      acc[0][0] += a0 * b0; acc[0][1] += a0 * b1; acc[0][2] += a0 * b2; acc[0][3] += a0 * b3;
      acc[1][0] += a1 * b0; acc[1][1] += a1 * b1; acc[1][2] += a1 * b2; acc[1][3] += a1 * b3;
      acc[2][0] += a2 * b0; acc[2][1] += a2 * b1; acc[2][2] += a2 * b2; acc[2][3] += a2 * b3;
      acc[3][0] += a3 * b0; acc[3][1] += a3 * b1; acc[3][2] += a3 * b2; acc[3][3] += a3 * b3;
    }
    __syncthreads();
  }

#pragma unroll
  for (int i = 0; i < 4; ++i) {
    int row = rb + ty * 4 + i;
#pragma unroll
    for (int j = 0; j < 4; ++j) {
      int col = nb + tx * 4 + j;
      float v = acc[i][j] + bias[col];
      if constexpr (EPI == EP_PLAIN) {
        C0[(size_t)row * N + col] = v;
      } else if constexpr (EPI == EP_SPLIT) {
        if (col < 192) C0[(size_t)row * 192 + col] = v;
        else           C1[(size_t)row * 192 + col - 192] = v;
      } else if constexpr (EPI == EP_RESID) {
        C0[(size_t)row * N + col] = v + resid[(size_t)row * N + col];
      } else if constexpr (EPI == EP_GELU) {
        C0[(size_t)row * N + col] = 0.5f * v * (1.f + erff(v * 0.70710678118654752f));
      }
    }
  }
}

// ---------------- Attention: one block per (window, head) ------------------
// Gathers K/V head-slices for the 216 neighborhood tokens into LDS, computes
// S = (q*0.25) @ K^T, row softmax, O = P @ V, scatters to token-major layout.
__global__ __launch_bounds__(256) void attn_kernel(const float* __restrict__ qbuf,
                                                   const float* __restrict__ kbuf,
                                                   const float* __restrict__ vbuf,
                                                   const float* __restrict__ bkv,
                                                   float* __restrict__ obuf) {
  __shared__ float Ks[216][20];  // pad 20: 16B-aligned rows, conflict-free b128 reads
  __shared__ float Vs[216][20];
  __shared__ float Qs[8][16];
  __shared__ float S[8][216];

  const int b = blockIdx.x;   // window
  const int h = blockIdx.y;   // head
  const int tid = threadIdx.x;
  const int ww = b & 15, wh = (b >> 4) & 15, wd = b >> 8;

  // gather K/V (216 tokens x 16 ch for this head)
  for (int idx = tid; idx < 216 * 16; idx += 256) {
    int m = idx >> 4, d = idx & 15;
    int lw = m & 1;  int t1 = m >> 1;
    int dk = t1 % 3; int t2 = t1 / 3;
    int lh = t2 & 1; int t3 = t2 >> 1;
    int dj = t3 % 3; int t4 = t3 / 3;
    int ld = t4 & 1; int di = t4 >> 1;
    int nwd = wd + di - 1, nwh = wh + dj - 1, nww = ww + dk - 1;
    int slab = di * 9 + dj * 3 + dk;
    float kk, vv;
    if (nwd < 0 || nwd > 15 || nwh < 0 || nwh > 15 || nww < 0 || nww > 15 || slab == 20) {
      kk = bkv[h * 16 + d];          // projection of zero row = bias
      vv = bkv[192 + h * 16 + d];
    } else {
      int z = nwd * 2 + ld, y = nwh * 2 + lh, xx = nww * 2 + lw;
      int t = (z * 32 + y) * 32 + xx;
      kk = kbuf[(size_t)t * 192 + h * 16 + d];
      vv = vbuf[(size_t)t * 192 + h * 16 + d];
    }
    Ks[m][d] = kk;
    Vs[m][d] = vv;
  }
  // load Q (8 x 16), pre-scaled
  if (tid < 128) {
    int n = tid >> 4, d = tid & 15;
    int ld = n >> 2, lh = (n >> 1) & 1, lw = n & 1;
    int z = wd * 2 + ld, y = wh * 2 + lh, xx = ww * 2 + lw;
    int t = (z * 32 + y) * 32 + xx;
    Qs[n][d] = qbuf[(size_t)t * 192 + h * 16 + d] * 0.25f;  // 1/sqrt(16)
  }
  __syncthreads();

  // S[n][m] = q.k
  for (int idx = tid; idx < 8 * 216; idx += 256) {
    int n = idx / 216, m = idx % 216;
    float s = 0.f;
#pragma unroll
    for (int d = 0; d < 16; ++d) s += Qs[n][d] * Ks[m][d];
    S[n][m] = s;
  }
  __syncthreads();

  // softmax per row (one wave per row, rows wave and wave+4)
  int wave = tid >> 6, lane = tid & 63;
  for (int n = wave; n < 8; n += 4) {
    float mx = -1e30f;
    for (int m = lane; m < 216; m += 64) mx = fmaxf(mx, S[n][m]);
#pragma unroll
    for (int off = 32; off; off >>= 1) mx = fmaxf(mx, __shfl_xor(mx, off));
    float sum = 0.f;
    for (int m = lane; m < 216; m += 64) {
      float e = __expf(S[n][m] - mx);
      S[n][m] = e;
      sum += e;
    }
#pragma unroll
    for (int off = 32; off; off >>= 1) sum += __shfl_xor(sum, off);
    float inv = 1.f / sum;
    for (int m = lane; m < 216; m += 64) S[n][m] *= inv;
  }
  __syncthreads();

  // O[n][d] = P @ V, scatter to token-major
  if (tid < 128) {
    int n = tid >> 4, d = tid & 15;
    float o = 0.f;
    for (int m = 0; m < 216; ++m) o += S[n][m] * Vs[m][d];
    int ld = n >> 2, lh = (n >> 1) & 1, lw = n & 1;
    int z = wd * 2 + ld, y = wh * 2 + lh, xx = ww * 2 + lw;
    int t = (z * 32 + y) * 32 + xx;
    obuf[(size_t)t * 192 + h * 16 + d] = o;
  }
}

extern "C" void kernel_launch(void* const* d_in, const int* in_sizes, int n_in,
                              void* d_out, int out_size, void* d_ws, size_t ws_size,
                              hipStream_t stream) {
  const float* x   = (const float*)d_in[0];
  const float* xa  = (const float*)d_in[1];
  const float* n1g = (const float*)d_in[2];
  const float* n1b = (const float*)d_in[3];
  const float* n2g = (const float*)d_in[4];
  const float* n2b = (const float*)d_in[5];
  const float* Wq  = (const float*)d_in[6];
  const float* bq  = (const float*)d_in[7];
  const float* Wkv = (const float*)d_in[8];
  const float* bkv = (const float*)d_in[9];
  const float* Wp  = (const float*)d_in[10];
  const float* bp  = (const float*)d_in[11];
  const float* W1  = (const float*)d_in[12];
  const float* b1  = (const float*)d_in[13];
  const float* W2  = (const float*)d_in[14];
  const float* b2  = (const float*)d_in[15];

  float* ws = (float*)d_ws;
  const size_t TB = (size_t)TOK * 192;
  // buffer aliasing (lifetime-safe): total ws use = 5*TB floats = 125.8 MB
  float* xn     = ws + 0 * TB;  // LN1(x)      -> later attn_out
  float* xan    = ws + 1 * TB;  // LN1(xa)     -> later x1
  float* qb     = ws + 2 * TB;  // Q           -> later LN2(x1)
  float* kb     = ws + 3 * TB;  // K           -> later mlp hidden (lo half)
  float* vb     = ws + 4 * TB;  // V           -> later mlp hidden (hi half)
  float* attn_o = xn;
  float* x1     = xan;
  float* xn2    = qb;
  float* hmlp   = kb;           // [TOK,384] spans kb..vb contiguously

  ln_kernel<<<TOK / 4, 256, 0, stream>>>(x, xn, n1g, n1b);
  ln_kernel<<<TOK / 4, 256, 0, stream>>>(xa, xan, n1g, n1b);

  gemm_ep<EP_PLAIN, 192, 192><<<dim3(TOK / 64, 3), 256, 0, stream>>>(xn, Wq, bq, nullptr, qb, nullptr);
  gemm_ep<EP_SPLIT, 192, 384><<<dim3(TOK / 64, 6), 256, 0, stream>>>(xan, Wkv, bkv, nullptr, kb, vb);

  attn_kernel<<<dim3(NWIN, 12), 256, 0, stream>>>(qb, kb, vb, bkv, attn_o);

  gemm_ep<EP_RESID, 192, 192><<<dim3(TOK / 64, 3), 256, 0, stream>>>(attn_o, Wp, bp, x, x1, nullptr);

  ln_kernel<<<TOK / 4, 256, 0, stream>>>(x1, xn2, n2g, n2b);

  gemm_ep<EP_GELU, 192, 384><<<dim3(TOK / 64, 6), 256, 0, stream>>>(xn2, W1, b1, nullptr, hmlp, nullptr);
  gemm_ep<EP_RESID, 384, 192><<<dim3(TOK / 64, 3), 256, 0, stream>>>(hmlp, W2, b2, x1, (float*)d_out, nullptr);
}

// Round 2
// 753.739 us; speedup vs baseline: 1.2477x; 1.2477x over previous
//
#include <hip/hip_runtime.h>
#include <hip/hip_bf16.h>
#include <math.h>

// CrossTransformerBlock3D: D=H=W=32, DIM=192, HEADS=12, HD=16, WS=2x2x2
// nW=4096 windows, N=8 queries/window, M=216 keys/window (3x3x3 neighborhood)
// K/V projected ONCE per base token (27x fewer KV FLOPs than reference).
// Attention = bf16 MFMA (16x16x32), one block per (window, 6-head half).

#define TOK 32768
#define NWIN 4096

typedef float f32x4 __attribute__((ext_vector_type(4)));
typedef short bf16x8 __attribute__((ext_vector_type(8)));
typedef short bf16x4 __attribute__((ext_vector_type(4)));

static __device__ __forceinline__ short f2bf(float x) {
  __hip_bfloat16 h = __float2bfloat16(x);
  return __builtin_bit_cast(short, h);
}

enum { EP_PLAIN = 0, EP_SPLIT = 1, EP_RESID = 2, EP_GELU = 3 };

// ---------------- LayerNorm: one wave per token, 4 tokens per block ----------
__global__ __launch_bounds__(256) void ln_kernel(const float* __restrict__ in,
                                                 float* __restrict__ out,
                                                 const float* __restrict__ g,
                                                 const float* __restrict__ b) {
  int token = blockIdx.x * 4 + (threadIdx.x >> 6);
  int lane = threadIdx.x & 63;
  const float* row = in + (size_t)token * 192;
  float v0 = row[lane], v1 = row[lane + 64], v2 = row[lane + 128];
  float s = v0 + v1 + v2;
#pragma unroll
  for (int off = 32; off; off >>= 1) s += __shfl_xor(s, off);
  float mean = s * (1.f / 192.f);
  float d0 = v0 - mean, d1 = v1 - mean, d2 = v2 - mean;
  float vs = d0 * d0 + d1 * d1 + d2 * d2;
#pragma unroll
  for (int off = 32; off; off >>= 1) vs += __shfl_xor(vs, off);
  float rstd = rsqrtf(vs * (1.f / 192.f) + 1e-5f);
  float* orow = out + (size_t)token * 192;
  orow[lane] = d0 * rstd * g[lane] + b[lane];
  orow[lane + 64] = d1 * rstd * g[lane + 64] + b[lane + 64];
  orow[lane + 128] = d2 * rstd * g[lane + 128] + b[lane + 128];
}

// ---------------- fp32 GEMM, 64x64 tile, 4x4 per-thread micro-tile ----------
template <int EPI, int K, int N>
__global__ __launch_bounds__(256) void gemm_ep(const float* __restrict__ A,
                                               const float* __restrict__ B,
                                               const float* __restrict__ bias,
                                               const float* __restrict__ resid,
                                               float* __restrict__ C0,
                                               float* __restrict__ C1) {
  __shared__ float As[16][68];
  __shared__ float Bs[16][68];
  const int tid = threadIdx.x;
  const int tx = tid & 15, ty = tid >> 4;
  const int rb = blockIdx.x * 64;
  const int nb = blockIdx.y * 64;
  float acc[4][4] = {};

#pragma unroll 1
  for (int k0 = 0; k0 < K; k0 += 16) {
#pragma unroll
    for (int p = 0; p < 4; ++p) {
      int idx = tid + p * 256;
      int kk = idx & 15, row = idx >> 4;
      As[kk][row] = A[(size_t)(rb + row) * K + k0 + kk];
    }
#pragma unroll
    for (int p = 0; p < 4; ++p) {
      int idx = tid + p * 256;
      int n = idx & 63, kk = idx >> 6;
      Bs[kk][n] = B[(size_t)(k0 + kk) * N + nb + n];
    }
    __syncthreads();
#pragma unroll
    for (int kk = 0; kk < 16; ++kk) {
      float a0 = As[kk][ty * 4 + 0], a1 = As[kk][ty * 4 + 1];
      float a2 = As[kk][ty * 4 + 2], a3 = As[kk][ty * 4 + 3];
      float b0 = Bs[kk][tx * 4 + 0], b1 = Bs[kk][tx * 4 + 1];
      float b2 = Bs[kk][tx * 4 + 2], b3 = Bs[kk][tx * 4 + 3];
      acc[0][0] += a0 * b0; acc[0][1] += a0 * b1; acc[0][2] += a0 * b2; acc[0][3] += a0 * b3;
      acc[1][0] += a1 * b0; acc[1][1] += a1 * b1; acc[1][2] += a1 * b2; acc[1][3] += a1 * b3;
      acc[2][0] += a2 * b0; acc[2][1] += a2 * b1; acc[2][2] += a2 * b2; acc[2][3] += a2 * b3;
      acc[3][0] += a3 * b0; acc[3][1] += a3 * b1; acc[3][2] += a3 * b2; acc[3][3] += a3 * b3;
    }
    __syncthreads();
  }

#pragma unroll
  for (int i = 0; i < 4; ++i) {
    int row = rb + ty * 4 + i;
#pragma unroll
    for (int j = 0; j < 4; ++j) {
      int col = nb + tx * 4 + j;
      float v = acc[i][j] + bias[col];
      if constexpr (EPI == EP_PLAIN) {
        C0[(size_t)row * N + col] = v;
      } else if constexpr (EPI == EP_SPLIT) {
        if (col < 192) C0[(size_t)row * 192 + col] = v;
        else           C1[(size_t)row * 192 + col - 192] = v;
      } else if constexpr (EPI == EP_RESID) {
        C0[(size_t)row * N + col] = v + resid[(size_t)row * N + col];
      } else if constexpr (EPI == EP_GELU) {
        C0[(size_t)row * N + col] = 0.5f * v * (1.f + erff(v * 0.70710678118654752f));
      }
    }
  }
}

// ---------------- Attention via bf16 MFMA ------------------------------------
// Block = (window, head-half): 384 threads = 6 waves, 1 head per wave.
// Phase 0: gather indices + Q staging (bf16, x0.25, rows 8-15 zeroed)
// Phase 1: K staging token-major [6][224][16] bf16, channel-half XOR swizzle
// Phase 2: per-wave QK^T (14 MFMA), in-register softmax, P -> LDS bf16
// Phase 3: V staging channel-major [6][16][232] bf16 (overwrites K region)
// Phase 4: per-wave PV (7 MFMA), scatter O (f32, token-major)
__global__ __launch_bounds__(384, 3) void attn_mfma(const float* __restrict__ qbuf,
                                                    const float* __restrict__ kbuf,
                                                    const float* __restrict__ vbuf,
                                                    const float* __restrict__ bkv,
                                                    float* __restrict__ obuf) {
  __shared__ int tIdx[216];
  __shared__ __align__(16) short Qs[16 * 104];       // [16 rows][104 pad] (96 chans used)
  __shared__ __align__(16) short KVs[6 * 16 * 232];  // K view [6][224][16] / V view [6][16][232]
  __shared__ __align__(16) short Ps[6 * 8 * 232];    // P [6][8 rows][232 pad]

  const int tid = threadIdx.x;
  const unsigned bx = blockIdx.x;
  const int b = ((bx & 7) << 9) | (bx >> 3);  // XCD-chunk swizzle: 8 chunks x 512 windows
  const int hb = blockIdx.y * 6;              // head base (0 or 6)
  const int ww = b & 15, wh = (b >> 4) & 15, wd = b >> 8;

  // ---- phase 0: neighborhood indices + Q staging
  if (tid < 216) {
    int m = tid;
    int lw = m & 1;  int t1 = m >> 1;
    int dk = t1 % 3; int t2 = t1 / 3;
    int lh = t2 & 1; int t3 = t2 >> 1;
    int dj = t3 % 3; int t4 = t3 / 3;
    int ld = t4 & 1; int di = t4 >> 1;
    int nwd = wd + di - 1, nwh = wh + dj - 1, nww = ww + dk - 1;
    int slab = di * 9 + dj * 3 + dk;
    int t = -1;
    if (nwd >= 0 && nwd <= 15 && nwh >= 0 && nwh <= 15 && nww >= 0 && nww <= 15 && slab != 20) {
      int z = nwd * 2 + ld, y = nwh * 2 + lh, xx = nww * 2 + lw;
      t = (z * 32 + y) * 32 + xx;
    }
    tIdx[m] = t;
  }
  if (tid < 192) {  // stage Q: 8 tokens x 24 float4
    int n = tid / 24, cb = tid % 24;
    int lc = cb * 4;
    int ldq = n >> 2, lhq = (n >> 1) & 1, lwq = n & 1;
    int z = wd * 2 + ldq, y = wh * 2 + lhq, xx = ww * 2 + lwq;
    int t = (z * 32 + y) * 32 + xx;
    float4 q4 = *(const float4*)(qbuf + (size_t)t * 192 + hb * 16 + lc);
    bf16x4 qq;
    qq.x = f2bf(q4.x * 0.25f); qq.y = f2bf(q4.y * 0.25f);
    qq.z = f2bf(q4.z * 0.25f); qq.w = f2bf(q4.w * 0.25f);
    *(bf16x4*)(Qs + n * 104 + lc) = qq;
  }
  if (tid < 104) {  // zero Q rows 8-15 (NaN hygiene for A-frag lanes with row>=8)
#pragma unroll
    for (int r = 8; r < 16; ++r) Qs[r * 104 + tid] = 0;
  }
  __syncthreads();

  // ---- phase 1: K staging (216 tokens x 24 float4, swizzled token-major)
  for (unsigned idx = tid; idx < 216u * 24u; idx += 384u) {
    unsigned m = idx / 24u, cb = idx % 24u;
    int lc = cb * 4;
    int hl = lc >> 4, d0 = lc & 15;
    int t = tIdx[m];
    float4 k4 = (t >= 0) ? *(const float4*)(kbuf + (size_t)t * 192 + hb * 16 + lc)
                         : *(const float4*)(bkv + hb * 16 + lc);
    bf16x4 kk;
    kk.x = f2bf(k4.x); kk.y = f2bf(k4.y); kk.z = f2bf(k4.z); kk.w = f2bf(k4.w);
    int blk = (d0 >> 3) ^ ((m >> 2) & 1);  // channel-half swap by token bit2: 2-way banks
    *(bf16x4*)(KVs + ((unsigned)hl * 224u + m) * 16u + blk * 8 + (d0 & 7)) = kk;
  }
  __syncthreads();

  // ---- phase 2: per-wave QK^T + softmax + P write
  const int wave = tid >> 6, lane = tid & 63;
  const int hl = wave;            // local head 0..5
  const int lrow = lane & 15, lkg = lane >> 4;

  bf16x8 qa = (bf16x8)0;
  if (lkg < 2) qa = *(const bf16x8*)(Qs + lrow * 104 + hl * 16 + lkg * 8);

  f32x4 s[14];
  const f32x4 zero4 = {0.f, 0.f, 0.f, 0.f};
#pragma unroll
  for (int t = 0; t < 14; ++t) {
    bf16x8 kf = (bf16x8)0;
    if (lkg < 2) {
      int tok = t * 16 + lrow;
      int blk = lkg ^ ((tok >> 2) & 1);
      kf = *(const bf16x8*)(KVs + ((unsigned)hl * 224u + tok) * 16u + blk * 8);
    }
    s[t] = __builtin_amdgcn_mfma_f32_16x16x32_bf16(qa, kf, zero4, 0, 0, 0);
  }
  if (lrow >= 8) {  // mask padded cols 216..223 (tile 13)
    s[13][0] = -1e30f; s[13][1] = -1e30f; s[13][2] = -1e30f; s[13][3] = -1e30f;
  }
#pragma unroll
  for (int r = 0; r < 4; ++r) {
    float mx = s[0][r];
#pragma unroll
    for (int t = 1; t < 14; ++t) mx = fmaxf(mx, s[t][r]);
    mx = fmaxf(mx, __shfl_xor(mx, 1));
    mx = fmaxf(mx, __shfl_xor(mx, 2));
    mx = fmaxf(mx, __shfl_xor(mx, 4));
    mx = fmaxf(mx, __shfl_xor(mx, 8));
    float sum = 0.f;
#pragma unroll
    for (int t = 0; t < 14; ++t) {
      float p = __expf(s[t][r] - mx);
      s[t][r] = p;
      sum += p;
    }
    sum += __shfl_xor(sum, 1);
    sum += __shfl_xor(sum, 2);
    sum += __shfl_xor(sum, 4);
    sum += __shfl_xor(sum, 8);
    float inv = 1.f / sum;
    if (lane < 32) {
      int row = (lane >> 4) * 4 + r;  // query 0..7
#pragma unroll
      for (int t = 0; t < 14; ++t) {
        Ps[((unsigned)hl * 8u + row) * 232u + t * 16 + lrow] = f2bf(s[t][r] * inv);
      }
    }
  }
  __syncthreads();

  // ---- phase 3: V staging, channel-major [6][16][232], m>=216 zeroed
  for (unsigned idx = tid; idx < 224u * 24u; idx += 384u) {
    unsigned m = idx / 24u, cb = idx % 24u;
    int lc = cb * 4;
    int hlv = lc >> 4, d0 = lc & 15;
    float4 v4 = {0.f, 0.f, 0.f, 0.f};
    if (m < 216u) {
      int t = tIdx[m];
      v4 = (t >= 0) ? *(const float4*)(vbuf + (size_t)t * 192 + hb * 16 + lc)
                    : *(const float4*)(bkv + 192 + hb * 16 + lc);
    }
    KVs[((unsigned)hlv * 16u + d0 + 0) * 232u + m] = f2bf(v4.x);
    KVs[((unsigned)hlv * 16u + d0 + 1) * 232u + m] = f2bf(v4.y);
    KVs[((unsigned)hlv * 16u + d0 + 2) * 232u + m] = f2bf(v4.z);
    KVs[((unsigned)hlv * 16u + d0 + 3) * 232u + m] = f2bf(v4.w);
  }
  __syncthreads();

  // ---- phase 4: PV + store
  f32x4 o = {0.f, 0.f, 0.f, 0.f};
#pragma unroll
  for (int kk = 0; kk < 7; ++kk) {
    bf16x8 pa = (bf16x8)0;
    if (lrow < 8)
      pa = *(const bf16x8*)(Ps + ((unsigned)hl * 8u + lrow) * 232u + kk * 32 + lkg * 8);
    bf16x8 vf = *(const bf16x8*)(KVs + ((unsigned)hl * 16u + lrow) * 232u + kk * 32 + lkg * 8);
    o = __builtin_amdgcn_mfma_f32_16x16x32_bf16(pa, vf, o, 0, 0, 0);
  }
  if (lane < 32) {
    const int h = hb + hl;
#pragma unroll
    for (int r = 0; r < 4; ++r) {
      int n = (lane >> 4) * 4 + r;
      int ldq = n >> 2, lhq = (n >> 1) & 1, lwq = n & 1;
      int z = wd * 2 + ldq, y = wh * 2 + lhq, xx = ww * 2 + lwq;
      int t = (z * 32 + y) * 32 + xx;
      obuf[(size_t)t * 192 + h * 16 + lrow] = o[r];
    }
  }
}

extern "C" void kernel_launch(void* const* d_in, const int* in_sizes, int n_in,
                              void* d_out, int out_size, void* d_ws, size_t ws_size,
                              hipStream_t stream) {
  const float* x   = (const float*)d_in[0];
  const float* xa  = (const float*)d_in[1];
  const float* n1g = (const float*)d_in[2];
  const float* n1b = (const float*)d_in[3];
  const float* n2g = (const float*)d_in[4];
  const float* n2b = (const float*)d_in[5];
  const float* Wq  = (const float*)d_in[6];
  const float* bq  = (const float*)d_in[7];
  const float* Wkv = (const float*)d_in[8];
  const float* bkv = (const float*)d_in[9];
  const float* Wp  = (const float*)d_in[10];
  const float* bp  = (const float*)d_in[11];
  const float* W1  = (const float*)d_in[12];
  const float* b1  = (const float*)d_in[13];
  const float* W2  = (const float*)d_in[14];
  const float* b2  = (const float*)d_in[15];

  float* ws = (float*)d_ws;
  const size_t TB = (size_t)TOK * 192;
  float* xn     = ws + 0 * TB;  // LN1(x)      -> later attn_out
  float* xan    = ws + 1 * TB;  // LN1(xa)     -> later x1
  float* qb     = ws + 2 * TB;  // Q           -> later LN2(x1)
  float* kb     = ws + 3 * TB;  // K           -> later mlp hidden (lo half)
  float* vb     = ws + 4 * TB;  // V           -> later mlp hidden (hi half)
  float* attn_o = xn;
  float* x1     = xan;
  float* xn2    = qb;
  float* hmlp   = kb;           // [TOK,384] spans kb..vb contiguously

  ln_kernel<<<TOK / 4, 256, 0, stream>>>(x, xn, n1g, n1b);
  ln_kernel<<<TOK / 4, 256, 0, stream>>>(xa, xan, n1g, n1b);

  gemm_ep<EP_PLAIN, 192, 192><<<dim3(TOK / 64, 3), 256, 0, stream>>>(xn, Wq, bq, nullptr, qb, nullptr);
  gemm_ep<EP_SPLIT, 192, 384><<<dim3(TOK / 64, 6), 256, 0, stream>>>(xan, Wkv, bkv, nullptr, kb, vb);

  attn_mfma<<<dim3(NWIN, 2), 384, 0, stream>>>(qb, kb, vb, bkv, attn_o);

  gemm_ep<EP_RESID, 192, 192><<<dim3(TOK / 64, 3), 256, 0, stream>>>(attn_o, Wp, bp, x, x1, nullptr);

  ln_kernel<<<TOK / 4, 256, 0, stream>>>(x1, xn2, n2g, n2b);

  gemm_ep<EP_GELU, 192, 384><<<dim3(TOK / 64, 6), 256, 0, stream>>>(xn2, W1, b1, nullptr, hmlp, nullptr);
  gemm_ep<EP_RESID, 384, 192><<<dim3(TOK / 64, 3), 256, 0, stream>>>(hmlp, W2, b2, x1, (float*)d_out, nullptr);
}